// Round 1
// baseline (487.217 us; speedup 1.0000x reference)
//
#include <hip/hip_runtime.h>

// ---------------------------------------------------------------------------
// Generalized causal attention, MI355X (gfx950).
// Pipeline: f32->f16 convert -> QKV GEMM (MFMA, global_load_lds) ->
// in-place head-LN (q scaled by hd^-0.5*log2e) -> V transpose ->
// flash attention (exp2-domain online softmax) -> proj GEMM (+bias) fp32 out.
// ---------------------------------------------------------------------------

using f16x8 = __attribute__((ext_vector_type(8))) _Float16;
using f32x4 = __attribute__((ext_vector_type(4))) float;

#define MFMA(a, b, c) __builtin_amdgcn_mfma_f32_16x16x32_f16(a, b, c, 0, 0, 0)

__device__ __forceinline__ void gload_lds16(const void* g, void* l) {
  // LDS dest = wave-uniform base + lane*16 (HW behavior); global src per-lane.
  __builtin_amdgcn_global_load_lds(
      (const __attribute__((address_space(1))) unsigned int*)g,
      (__attribute__((address_space(3))) unsigned int*)l, 16, 0, 0);
}

// ---------------------------------------------------------------------------
__global__ __launch_bounds__(256) void f32_to_f16_kernel(
    const float* __restrict__ in, _Float16* __restrict__ out, int n) {
  int i = (blockIdx.x * 256 + threadIdx.x) * 8;
  if (i >= n) return;
  float4 a = *(const float4*)(in + i);
  float4 b = *(const float4*)(in + i + 4);
  f16x8 o;
  o[0] = (_Float16)a.x; o[1] = (_Float16)a.y; o[2] = (_Float16)a.z; o[3] = (_Float16)a.w;
  o[4] = (_Float16)b.x; o[5] = (_Float16)b.y; o[6] = (_Float16)b.z; o[7] = (_Float16)b.w;
  *(f16x8*)(out + i) = o;
}

// ---------------------------------------------------------------------------
// C[M,N] = A[M,K] @ B[N,K]^T, 128x128 tile, BK=32, 4 waves (2x2), m97-style.
template <bool F16OUT>
__global__ __launch_bounds__(256) void gemm_bt(
    const _Float16* __restrict__ A, const _Float16* __restrict__ B,
    void* __restrict__ Cout, const float* __restrict__ bias,
    int M, int N, int K) {
  __shared__ __align__(16) _Float16 As[128 * 32];  // [128 rows][32 k]
  __shared__ __align__(16) _Float16 Bs[128 * 32];
  const int tid = threadIdx.x;
  const int w = tid >> 6, lane = tid & 63;
  const int c = lane & 15, g = lane >> 4;
  const long mbase = (long)blockIdx.x * 128;
  const long nbase = (long)blockIdx.y * 128;
  const int wm = (w >> 1) * 64, wn = (w & 1) * 64;
  // staging: per wave 2 chunks of 1KB; lane covers 16B at row srow, col scol
  const int srow = w * 32 + (lane >> 2);
  const int scol = (lane & 3) * 8;

  f32x4 acc[4][4];
#pragma unroll
  for (int i = 0; i < 4; ++i)
#pragma unroll
    for (int j = 0; j < 4; ++j) acc[i][j] = f32x4{0.f, 0.f, 0.f, 0.f};

  for (int kt = 0; kt < K; kt += 32) {
    __syncthreads();  // previous tile consumed
    gload_lds16(A + (mbase + srow) * K + kt + scol, As + w * 1024);
    gload_lds16(A + (mbase + srow + 16) * K + kt + scol, As + w * 1024 + 512);
    gload_lds16(B + (nbase + srow) * K + kt + scol, Bs + w * 1024);
    gload_lds16(B + (nbase + srow + 16) * K + kt + scol, Bs + w * 1024 + 512);
    __syncthreads();  // drains vmcnt(0), staging visible
    f16x8 af[4], bfr[4];
#pragma unroll
    for (int mt = 0; mt < 4; ++mt)
      af[mt] = *(const f16x8*)(As + (wm + mt * 16 + c) * 32 + g * 8);
#pragma unroll
    for (int nt = 0; nt < 4; ++nt)
      bfr[nt] = *(const f16x8*)(Bs + (wn + nt * 16 + c) * 32 + g * 8);
#pragma unroll
    for (int mt = 0; mt < 4; ++mt)
#pragma unroll
      for (int nt = 0; nt < 4; ++nt)
        acc[mt][nt] = MFMA(af[mt], bfr[nt], acc[mt][nt]);
  }
#pragma unroll
  for (int nt = 0; nt < 4; ++nt) {
    const long col = nbase + wn + nt * 16 + c;
    const float bv = bias ? bias[col] : 0.f;
#pragma unroll
    for (int mt = 0; mt < 4; ++mt)
#pragma unroll
      for (int r = 0; r < 4; ++r) {
        const long row = mbase + wm + mt * 16 + g * 4 + r;
        const float v = acc[mt][nt][r] + bv;
        if constexpr (F16OUT)
          ((_Float16*)Cout)[row * N + col] = (_Float16)v;
        else
          ((float*)Cout)[row * N + col] = v;
      }
  }
}

// ---------------------------------------------------------------------------
// In-place LN over hd=64 for q (e<1024, scaled by 0.125*log2e) and k (1024..2047).
// One wave = 512 contiguous elements = 8 head-segments; 8 lanes per segment.
__global__ __launch_bounds__(256) void ln_pack_kernel(
    _Float16* __restrict__ qkv, const float* __restrict__ qg,
    const float* __restrict__ qb, const float* __restrict__ kg,
    const float* __restrict__ kb) {
  const int W = blockIdx.x * 4 + (threadIdx.x >> 6);
  const int lane = threadIdx.x & 63;
  const long row = W >> 2;
  const int e = (W & 3) * 512 + (lane >> 3) * 64 + (lane & 7) * 8;
  const int t = e >> 10;  // 0=q, 1=k (wave-uniform)
  const int d0 = (lane & 7) * 8;
  _Float16* p = qkv + row * 3072 + e;
  f16x8 v = *(const f16x8*)p;
  float f[8], sum = 0.f, sq = 0.f;
#pragma unroll
  for (int j = 0; j < 8; ++j) { f[j] = (float)v[j]; sum += f[j]; sq += f[j] * f[j]; }
#pragma unroll
  for (int msk = 1; msk < 8; msk <<= 1) {
    sum += __shfl_xor(sum, msk);
    sq += __shfl_xor(sq, msk);
  }
  const float mu = sum * 0.015625f;
  const float var = sq * 0.015625f - mu * mu;
  const float rstd = rsqrtf(var + 1e-5f);
  const float* gamma = t ? kg : qg;
  const float* beta = t ? kb : qb;
  const float sc = t ? 1.f : 0.1803368801111204f;  // hd^-0.5 * log2(e)
  f16x8 o;
#pragma unroll
  for (int j = 0; j < 8; ++j)
    o[j] = (_Float16)(((f[j] - mu) * rstd * gamma[d0 + j] + beta[d0 + j]) * sc);
  *(f16x8*)p = o;
}

// ---------------------------------------------------------------------------
// V transpose: qkv v-part [l][d] -> Vt[nh][d][l] (rows contiguous in l).
__global__ __launch_bounds__(256) void transpose_v_kernel(
    const _Float16* __restrict__ qkv, _Float16* __restrict__ Vt) {
  __shared__ __align__(16) _Float16 tile[64][80];  // pad->16B-aligned rows
  const int nh = blockIdx.y;
  const long n = nh >> 4;
  const int h = nh & 15;
  const long lbase = (long)blockIdx.x * 64;
  const int t = threadIdx.x;
#pragma unroll
  for (int r = 0; r < 2; ++r) {
    const int l = (t + r * 256) >> 3;
    const int cc = (t & 7) * 8;
    f16x8 v = *(const f16x8*)(qkv + (n * 2048 + lbase + l) * 3072 + 2048 + h * 64 + cc);
    *(f16x8*)&tile[l][cc] = v;
  }
  __syncthreads();
  const int d = t >> 2, q = t & 3;
  f16x8 o0, o1;
#pragma unroll
  for (int i = 0; i < 8; ++i) {
    o0[i] = tile[q * 16 + i][d];
    o1[i] = tile[q * 16 + 8 + i][d];
  }
  _Float16* dst = Vt + ((long)nh * 64 + d) * 2048 + lbase + q * 16;
  *(f16x8*)dst = o0;
  *(f16x8*)(dst + 8) = o1;
}

// ---------------------------------------------------------------------------
// Flash attention, causal. Block=4 waves; wave owns 32 q-rows; KV tiles of 64.
// Q/K read strided from qkv (post-LN); V from Vt. exp2-domain softmax.
__global__ __launch_bounds__(256) void attn_kernel(
    const _Float16* __restrict__ qkv, const _Float16* __restrict__ Vt,
    _Float16* __restrict__ Ob) {
  __shared__ __align__(16) _Float16 Plds[4][32][88];  // per-wave P, padded rows
  const int w = threadIdx.x >> 6;
  const int lane = threadIdx.x & 63;
  const int c = lane & 15, g = lane >> 4;
  const int nh = blockIdx.y;
  const long n = nh >> 4;
  const int h = nh & 15;
  const int qlo = blockIdx.x * 128 + w * 32;

  const _Float16* Qp = qkv + n * 2048 * 3072 + h * 64;
  const _Float16* Kp = Qp + 1024;
  const _Float16* Vp = Vt + (long)nh * 64 * 2048;

  f16x8 qf[2][2];
#pragma unroll
  for (int qt = 0; qt < 2; ++qt)
#pragma unroll
    for (int db = 0; db < 2; ++db)
      qf[qt][db] = *(const f16x8*)(Qp + (long)(qlo + qt * 16 + c) * 3072 + db * 32 + g * 8);

  f32x4 acc[2][4];
  float m[2][4], ls[2][4];
#pragma unroll
  for (int qt = 0; qt < 2; ++qt) {
#pragma unroll
    for (int dt = 0; dt < 4; ++dt) acc[qt][dt] = f32x4{0.f, 0.f, 0.f, 0.f};
#pragma unroll
    for (int r = 0; r < 4; ++r) { m[qt][r] = -1e30f; ls[qt][r] = 0.f; }
  }

  const int nkv = (qlo + 95) >> 6;  // tiles with kbase <= qlo+31
  for (int kv = 0; kv < nkv; ++kv) {
    const int kbase = kv * 64;
    f32x4 s[2][4];
#pragma unroll
    for (int qt = 0; qt < 2; ++qt)
#pragma unroll
      for (int kt = 0; kt < 4; ++kt) s[qt][kt] = f32x4{0.f, 0.f, 0.f, 0.f};
    // S = Q @ K^T  (lane c = k-row for B fragments)
#pragma unroll
    for (int kt = 0; kt < 4; ++kt) {
      const _Float16* kp = Kp + (long)(kbase + kt * 16 + c) * 3072;
      f16x8 kf0 = *(const f16x8*)(kp + g * 8);
      f16x8 kf1 = *(const f16x8*)(kp + 32 + g * 8);
      s[0][kt] = MFMA(qf[0][0], kf0, s[0][kt]);
      s[0][kt] = MFMA(qf[0][1], kf1, s[0][kt]);
      s[1][kt] = MFMA(qf[1][0], kf0, s[1][kt]);
      s[1][kt] = MFMA(qf[1][1], kf1, s[1][kt]);
    }
    if (kbase + 63 > qlo) {  // causal mask on diagonal tiles
#pragma unroll
      for (int qt = 0; qt < 2; ++qt)
#pragma unroll
        for (int kt = 0; kt < 4; ++kt) {
          const int col = kbase + kt * 16 + c;
#pragma unroll
          for (int r = 0; r < 4; ++r)
            if (col > qlo + qt * 16 + g * 4 + r) s[qt][kt][r] = -1e30f;
        }
    }
    // online softmax (base 2)
#pragma unroll
    for (int qt = 0; qt < 2; ++qt) {
      float mt[4];
#pragma unroll
      for (int r = 0; r < 4; ++r)
        mt[r] = fmaxf(fmaxf(s[qt][0][r], s[qt][1][r]), fmaxf(s[qt][2][r], s[qt][3][r]));
#pragma unroll
      for (int r = 0; r < 4; ++r) {
        mt[r] = fmaxf(mt[r], __shfl_xor(mt[r], 1));
        mt[r] = fmaxf(mt[r], __shfl_xor(mt[r], 2));
        mt[r] = fmaxf(mt[r], __shfl_xor(mt[r], 4));
        mt[r] = fmaxf(mt[r], __shfl_xor(mt[r], 8));
      }
      float rsum[4] = {0.f, 0.f, 0.f, 0.f};
#pragma unroll
      for (int r = 0; r < 4; ++r) {
        const float mn = fmaxf(m[qt][r], mt[r]);
        const float al = exp2f(m[qt][r] - mn);
        m[qt][r] = mn;
        ls[qt][r] *= al;
#pragma unroll
        for (int dt = 0; dt < 4; ++dt) acc[qt][dt][r] *= al;
#pragma unroll
        for (int kt = 0; kt < 4; ++kt) {
          const float p = exp2f(s[qt][kt][r] - mn);
          s[qt][kt][r] = p;
          rsum[r] += p;
        }
      }
#pragma unroll
      for (int r = 0; r < 4; ++r) {
        rsum[r] += __shfl_xor(rsum[r], 1);
        rsum[r] += __shfl_xor(rsum[r], 2);
        rsum[r] += __shfl_xor(rsum[r], 4);
        rsum[r] += __shfl_xor(rsum[r], 8);
        ls[qt][r] += rsum[r];
      }
      // P to LDS (D-layout scatter), reread below as A fragments
#pragma unroll
      for (int kt = 0; kt < 4; ++kt)
#pragma unroll
        for (int r = 0; r < 4; ++r)
          Plds[w][qt * 16 + g * 4 + r][kt * 16 + c] = (_Float16)s[qt][kt][r];
    }
    f16x8 pa[2][2];
#pragma unroll
    for (int qt = 0; qt < 2; ++qt)
#pragma unroll
      for (int kb = 0; kb < 2; ++kb)
        pa[qt][kb] = *(const f16x8*)&Plds[w][qt * 16 + c][kb * 32 + g * 8];
    // O += P @ V  (V^T rows contiguous in Vt)
#pragma unroll
    for (int dt = 0; dt < 4; ++dt) {
      const _Float16* vp = Vp + (long)(dt * 16 + c) * 2048 + kbase + g * 8;
      f16x8 vf0 = *(const f16x8*)vp;
      f16x8 vf1 = *(const f16x8*)(vp + 32);
      acc[0][dt] = MFMA(pa[0][0], vf0, acc[0][dt]);
      acc[0][dt] = MFMA(pa[0][1], vf1, acc[0][dt]);
      acc[1][dt] = MFMA(pa[1][0], vf0, acc[1][dt]);
      acc[1][dt] = MFMA(pa[1][1], vf1, acc[1][dt]);
    }
  }
  // normalize + write O as [n, l, h*64+d] f16
#pragma unroll
  for (int qt = 0; qt < 2; ++qt) {
    float inv[4];
#pragma unroll
    for (int r = 0; r < 4; ++r) inv[r] = 1.f / ls[qt][r];
#pragma unroll
    for (int dt = 0; dt < 4; ++dt)
#pragma unroll
      for (int r = 0; r < 4; ++r) {
        const long rowq = qlo + qt * 16 + g * 4 + r;
        Ob[(n * 2048 + rowq) * 1024 + h * 64 + dt * 16 + c] =
            (_Float16)(acc[qt][dt][r] * inv[r]);
      }
  }
}

// ---------------------------------------------------------------------------
extern "C" void kernel_launch(void* const* d_in, const int* in_sizes, int n_in,
                              void* d_out, int out_size, void* d_ws, size_t ws_size,
                              hipStream_t stream) {
  const float* x = (const float*)d_in[0];
  // d_in[1] = attn_mask: fixed causal triu(k=1); handled analytically.
  const float* w_qkv = (const float*)d_in[2];
  const float* w_proj = (const float*)d_in[3];
  const float* b_proj = (const float*)d_in[4];
  const float* qg = (const float*)d_in[5];
  const float* qb = (const float*)d_in[6];
  const float* kg = (const float*)d_in[7];
  const float* kb = (const float*)d_in[8];

  char* ws = (char*)d_ws;
  _Float16* xb     = (_Float16*)(ws + 0);         // 16 MiB; reused as Ob later
  _Float16* wqkvb  = (_Float16*)(ws + 16777216);  // 6 MiB
  _Float16* wprojb = (_Float16*)(ws + 23068672);  // 2 MiB
  _Float16* qkvh   = (_Float16*)(ws + 25165824);  // 48 MiB [8192][3072]
  _Float16* Vt     = (_Float16*)(ws + 75497472);  // 16 MiB [64][64][2048]
  _Float16* Ob     = xb;                          // alias: xb dead after QKV GEMM

  f32_to_f16_kernel<<<4096, 256, 0, stream>>>(x, xb, 8388608);
  f32_to_f16_kernel<<<1536, 256, 0, stream>>>(w_qkv, wqkvb, 3145728);
  f32_to_f16_kernel<<<512, 256, 0, stream>>>(w_proj, wprojb, 1048576);

  gemm_bt<true><<<dim3(64, 24), 256, 0, stream>>>(xb, wqkvb, qkvh, nullptr,
                                                  8192, 3072, 1024);
  ln_pack_kernel<<<8192, 256, 0, stream>>>(qkvh, qg, qb, kg, kb);
  transpose_v_kernel<<<dim3(32, 64), 256, 0, stream>>>(qkvh, Vt);
  attn_kernel<<<dim3(16, 64), 256, 0, stream>>>(qkvh, Vt, Ob);
  gemm_bt<false><<<dim3(64, 8), 256, 0, stream>>>(Ob, wprojb, d_out, b_proj,
                                                  8192, 1024, 1024);
}

// Round 2
// 294.187 us; speedup vs baseline: 1.6561x; 1.6561x over previous
//
#include <hip/hip_runtime.h>

// ---------------------------------------------------------------------------
// Generalized causal attention, MI355X (gfx950).
// Pipeline: f32->f16 convert -> QKV GEMM (MFMA, global_load_lds) ->
// in-place head-LN (q scaled by hd^-0.5*log2e) -> V transpose ->
// flash attention (LDS-staged KV, dbuf, swizzled) -> proj GEMM (+bias) f32 out.
// ---------------------------------------------------------------------------

using f16x8 = __attribute__((ext_vector_type(8))) _Float16;
using f32x4 = __attribute__((ext_vector_type(4))) float;

#define MFMA(a, b, c) __builtin_amdgcn_mfma_f32_16x16x32_f16(a, b, c, 0, 0, 0)

__device__ __forceinline__ void gload_lds16(const void* g, void* l) {
  // LDS dest = wave-uniform base + lane*16 (HW behavior); global src per-lane.
  __builtin_amdgcn_global_load_lds(
      (const __attribute__((address_space(1))) unsigned int*)g,
      (__attribute__((address_space(3))) unsigned int*)l, 16, 0, 0);
}

// ---------------------------------------------------------------------------
__global__ __launch_bounds__(256) void f32_to_f16_kernel(
    const float* __restrict__ in, _Float16* __restrict__ out, int n) {
  int i = (blockIdx.x * 256 + threadIdx.x) * 8;
  if (i >= n) return;
  float4 a = *(const float4*)(in + i);
  float4 b = *(const float4*)(in + i + 4);
  f16x8 o;
  o[0] = (_Float16)a.x; o[1] = (_Float16)a.y; o[2] = (_Float16)a.z; o[3] = (_Float16)a.w;
  o[4] = (_Float16)b.x; o[5] = (_Float16)b.y; o[6] = (_Float16)b.z; o[7] = (_Float16)b.w;
  *(f16x8*)(out + i) = o;
}

// ---------------------------------------------------------------------------
// C[M,N] = A[M,K] @ B[N,K]^T, 128x128 tile, BK=32, 4 waves (2x2), m97-style.
template <bool F16OUT>
__global__ __launch_bounds__(256) void gemm_bt(
    const _Float16* __restrict__ A, const _Float16* __restrict__ B,
    void* __restrict__ Cout, const float* __restrict__ bias,
    int M, int N, int K) {
  __shared__ __align__(16) _Float16 As[128 * 32];  // [128 rows][32 k]
  __shared__ __align__(16) _Float16 Bs[128 * 32];
  const int tid = threadIdx.x;
  const int w = tid >> 6, lane = tid & 63;
  const int c = lane & 15, g = lane >> 4;
  const long mbase = (long)blockIdx.x * 128;
  const long nbase = (long)blockIdx.y * 128;
  const int wm = (w >> 1) * 64, wn = (w & 1) * 64;
  const int srow = w * 32 + (lane >> 2);
  const int scol = (lane & 3) * 8;

  f32x4 acc[4][4];
#pragma unroll
  for (int i = 0; i < 4; ++i)
#pragma unroll
    for (int j = 0; j < 4; ++j) acc[i][j] = f32x4{0.f, 0.f, 0.f, 0.f};

  for (int kt = 0; kt < K; kt += 32) {
    __syncthreads();  // previous tile consumed
    gload_lds16(A + (mbase + srow) * K + kt + scol, As + w * 1024);
    gload_lds16(A + (mbase + srow + 16) * K + kt + scol, As + w * 1024 + 512);
    gload_lds16(B + (nbase + srow) * K + kt + scol, Bs + w * 1024);
    gload_lds16(B + (nbase + srow + 16) * K + kt + scol, Bs + w * 1024 + 512);
    __syncthreads();  // drains vmcnt(0), staging visible
    f16x8 af[4], bfr[4];
#pragma unroll
    for (int mt = 0; mt < 4; ++mt)
      af[mt] = *(const f16x8*)(As + (wm + mt * 16 + c) * 32 + g * 8);
#pragma unroll
    for (int nt = 0; nt < 4; ++nt)
      bfr[nt] = *(const f16x8*)(Bs + (wn + nt * 16 + c) * 32 + g * 8);
#pragma unroll
    for (int mt = 0; mt < 4; ++mt)
#pragma unroll
      for (int nt = 0; nt < 4; ++nt)
        acc[mt][nt] = MFMA(af[mt], bfr[nt], acc[mt][nt]);
  }
#pragma unroll
  for (int nt = 0; nt < 4; ++nt) {
    const long col = nbase + wn + nt * 16 + c;
    const float bv = bias ? bias[col] : 0.f;
#pragma unroll
    for (int mt = 0; mt < 4; ++mt)
#pragma unroll
      for (int r = 0; r < 4; ++r) {
        const long row = mbase + wm + mt * 16 + g * 4 + r;
        const float v = acc[mt][nt][r] + bv;
        if constexpr (F16OUT)
          ((_Float16*)Cout)[row * N + col] = (_Float16)v;
        else
          ((float*)Cout)[row * N + col] = v;
      }
  }
}

// ---------------------------------------------------------------------------
// In-place LN over hd=64 for q (scaled by hd^-0.5*log2e) and k.
__global__ __launch_bounds__(256) void ln_pack_kernel(
    _Float16* __restrict__ qkv, const float* __restrict__ qg,
    const float* __restrict__ qb, const float* __restrict__ kg,
    const float* __restrict__ kb) {
  const int W = blockIdx.x * 4 + (threadIdx.x >> 6);
  const int lane = threadIdx.x & 63;
  const long row = W >> 2;
  const int e = (W & 3) * 512 + (lane >> 3) * 64 + (lane & 7) * 8;
  const int t = e >> 10;  // 0=q, 1=k (wave-uniform)
  const int d0 = (lane & 7) * 8;
  _Float16* p = qkv + row * 3072 + e;
  f16x8 v = *(const f16x8*)p;
  float f[8], sum = 0.f, sq = 0.f;
#pragma unroll
  for (int j = 0; j < 8; ++j) { f[j] = (float)v[j]; sum += f[j]; sq += f[j] * f[j]; }
#pragma unroll
  for (int msk = 1; msk < 8; msk <<= 1) {
    sum += __shfl_xor(sum, msk);
    sq += __shfl_xor(sq, msk);
  }
  const float mu = sum * 0.015625f;
  const float var = sq * 0.015625f - mu * mu;
  const float rstd = rsqrtf(var + 1e-5f);
  const float* gamma = t ? kg : qg;
  const float* beta = t ? kb : qb;
  const float sc = t ? 1.f : 0.1803368801111204f;  // hd^-0.5 * log2(e)
  f16x8 o;
#pragma unroll
  for (int j = 0; j < 8; ++j)
    o[j] = (_Float16)(((f[j] - mu) * rstd * gamma[d0 + j] + beta[d0 + j]) * sc);
  *(f16x8*)p = o;
}

// ---------------------------------------------------------------------------
// V transpose: qkv v-part [l][d] -> Vt[nh][d][l] (rows contiguous in l).
__global__ __launch_bounds__(256) void transpose_v_kernel(
    const _Float16* __restrict__ qkv, _Float16* __restrict__ Vt) {
  __shared__ __align__(16) _Float16 tile[64][80];
  const int nh = blockIdx.y;
  const long n = nh >> 4;
  const int h = nh & 15;
  const long lbase = (long)blockIdx.x * 64;
  const int t = threadIdx.x;
#pragma unroll
  for (int r = 0; r < 2; ++r) {
    const int l = (t + r * 256) >> 3;
    const int cc = (t & 7) * 8;
    f16x8 v = *(const f16x8*)(qkv + (n * 2048 + lbase + l) * 3072 + 2048 + h * 64 + cc);
    *(f16x8*)&tile[l][cc] = v;
  }
  __syncthreads();
  const int d = t >> 2, q = t & 3;
  f16x8 o0, o1;
#pragma unroll
  for (int i = 0; i < 8; ++i) {
    o0[i] = tile[q * 16 + i][d];
    o1[i] = tile[q * 16 + 8 + i][d];
  }
  _Float16* dst = Vt + ((long)nh * 64 + d) * 2048 + lbase + q * 16;
  *(f16x8*)dst = o0;
  *(f16x8*)(dst + 8) = o1;
}

// ---------------------------------------------------------------------------
// Flash attention, causal. Block = 4 waves; wave owns 32 q-rows; KV tiles of
// 64 rows staged cooperatively into LDS (double-buffered, XOR-swizzled via
// pre-swizzled global source — rule 21). exp2-domain online softmax.
// grid = (64 nh, 16 qtiles), longest q-tiles dispatched first.
__global__ __launch_bounds__(256) void attn_kernel(
    const _Float16* __restrict__ qkv, const _Float16* __restrict__ Vt,
    _Float16* __restrict__ Ob) {
  __shared__ __align__(16) _Float16 Ks[2][64 * 64];  // 8KB x2, rows=128B, swz
  __shared__ __align__(16) _Float16 Vs[2][64 * 64];  // V^T tiles, same layout
  __shared__ __align__(16) _Float16 Pl[4][32 * 64];  // per-wave P, swizzled
  const int w = threadIdx.x >> 6;
  const int lane = threadIdx.x & 63;
  const int c = lane & 15, g = lane >> 4;
  const int nh = blockIdx.x;
  const long n = nh >> 4;
  const int h = nh & 15;
  const int qtile = 15 - blockIdx.y;  // longest-first
  const int qlo_blk = qtile * 128;
  const int qlo = qlo_blk + w * 32;

  const _Float16* Qp = qkv + n * 2048 * 3072 + h * 64;
  const _Float16* Kq = Qp + 1024;                 // K base (row stride 3072)
  const _Float16* Vp = Vt + (long)nh * 64 * 2048; // V^T base (row stride 2048)

  // staging lane decomposition: row-in-chunk = lane>>3, 16B block = lane&7,
  // source column pre-swizzled by ^(row&7) so swizzled data lands linearly.
  const int sr8 = lane >> 3;
  const int scol = ((lane & 7) ^ sr8) * 8;

  const int nkv_blk = (qlo_blk + 191) >> 6;  // tiles needed by wave 3
  const int nkv_w = (qlo + 95) >> 6;         // tiles this wave computes

#define STAGE(buf, kv)                                                        \
  {                                                                           \
    const int kb_ = (kv) * 64;                                                \
    _Pragma("unroll") for (int i = 0; i < 2; ++i) {                           \
      const int idx = w * 2 + i;                                              \
      const int row = idx * 8 + sr8;                                          \
      gload_lds16(Kq + (long)(kb_ + row) * 3072 + scol, &Ks[buf][idx * 512]); \
      gload_lds16(Vp + (long)row * 2048 + kb_ + scol, &Vs[buf][idx * 512]);   \
    }                                                                         \
  }

  f16x8 qf[2][2];
#pragma unroll
  for (int qt = 0; qt < 2; ++qt)
#pragma unroll
    for (int db = 0; db < 2; ++db)
      qf[qt][db] = *(const f16x8*)(Qp + (long)(qlo + qt * 16 + c) * 3072 + db * 32 + g * 8);

  f32x4 acc[2][4];
  float m[2][4], ls[2][4];
#pragma unroll
  for (int qt = 0; qt < 2; ++qt) {
#pragma unroll
    for (int dt = 0; dt < 4; ++dt) acc[qt][dt] = f32x4{0.f, 0.f, 0.f, 0.f};
#pragma unroll
    for (int r = 0; r < 4; ++r) { m[qt][r] = -1e30f; ls[qt][r] = 0.f; }
  }

  STAGE(0, 0);

  const int sw = c & 7;  // read-side XOR (row&7 == c&7 for all frag reads)
  _Float16* Pw = Pl[w];

  for (int kv = 0; kv < nkv_blk; ++kv) {
    const int cur = kv & 1;
    __syncthreads();  // staging(kv) drained (vmcnt0); buf[cur^1] free
    if (kv + 1 < nkv_blk) STAGE(cur ^ 1, kv + 1);

    if (kv < nkv_w) {
      const int kbase = kv * 64;
      const _Float16* Kb = Ks[cur];
      const _Float16* Vb = Vs[cur];
      f32x4 s[2][4];
#pragma unroll
      for (int qt = 0; qt < 2; ++qt)
#pragma unroll
        for (int kt = 0; kt < 4; ++kt) s[qt][kt] = f32x4{0.f, 0.f, 0.f, 0.f};
      // S = Q @ K^T from swizzled LDS
      __builtin_amdgcn_s_setprio(1);
#pragma unroll
      for (int kt = 0; kt < 4; ++kt) {
        const _Float16* kr = Kb + (kt * 16 + c) * 64;
        f16x8 kf0 = *(const f16x8*)(kr + ((g ^ sw) << 3));
        f16x8 kf1 = *(const f16x8*)(kr + (((g ^ 4) ^ sw) << 3));
        s[0][kt] = MFMA(qf[0][0], kf0, s[0][kt]);
        s[0][kt] = MFMA(qf[0][1], kf1, s[0][kt]);
        s[1][kt] = MFMA(qf[1][0], kf0, s[1][kt]);
        s[1][kt] = MFMA(qf[1][1], kf1, s[1][kt]);
      }
      __builtin_amdgcn_s_setprio(0);
      if (kbase + 63 > qlo) {  // causal mask on diagonal tiles
#pragma unroll
        for (int qt = 0; qt < 2; ++qt)
#pragma unroll
          for (int kt = 0; kt < 4; ++kt) {
            const int col = kbase + kt * 16 + c;
#pragma unroll
            for (int r = 0; r < 4; ++r)
              if (col > qlo + qt * 16 + g * 4 + r) s[qt][kt][r] = -1e30f;
          }
      }
      // online softmax (base 2)
#pragma unroll
      for (int qt = 0; qt < 2; ++qt) {
        float mt[4];
#pragma unroll
        for (int r = 0; r < 4; ++r)
          mt[r] = fmaxf(fmaxf(s[qt][0][r], s[qt][1][r]), fmaxf(s[qt][2][r], s[qt][3][r]));
#pragma unroll
        for (int r = 0; r < 4; ++r) {
          mt[r] = fmaxf(mt[r], __shfl_xor(mt[r], 1));
          mt[r] = fmaxf(mt[r], __shfl_xor(mt[r], 2));
          mt[r] = fmaxf(mt[r], __shfl_xor(mt[r], 4));
          mt[r] = fmaxf(mt[r], __shfl_xor(mt[r], 8));
        }
        float rsum[4] = {0.f, 0.f, 0.f, 0.f};
#pragma unroll
        for (int r = 0; r < 4; ++r) {
          const float mn = fmaxf(m[qt][r], mt[r]);
          const float al = exp2f(m[qt][r] - mn);
          m[qt][r] = mn;
          ls[qt][r] *= al;
#pragma unroll
          for (int dt = 0; dt < 4; ++dt) acc[qt][dt][r] *= al;
#pragma unroll
          for (int kt = 0; kt < 4; ++kt) {
            const float p = exp2f(s[qt][kt][r] - mn);
            s[qt][kt][r] = p;
            rsum[r] += p;
          }
        }
#pragma unroll
        for (int r = 0; r < 4; ++r) {
          rsum[r] += __shfl_xor(rsum[r], 1);
          rsum[r] += __shfl_xor(rsum[r], 2);
          rsum[r] += __shfl_xor(rsum[r], 4);
          rsum[r] += __shfl_xor(rsum[r], 8);
          ls[qt][r] += rsum[r];
        }
        // P -> per-wave LDS, swizzled: elem(prow,pcol) at
        // prow*64 + ((pcol>>3 ^ (prow&7))<<3) + (pcol&7)
#pragma unroll
        for (int kt = 0; kt < 4; ++kt)
#pragma unroll
          for (int r = 0; r < 4; ++r) {
            const int prow = qt * 16 + g * 4 + r;
            const int pblk = (kt * 2 + (c >> 3)) ^ (prow & 7);
            Pw[prow * 64 + pblk * 8 + (c & 7)] = (_Float16)s[qt][kt][r];
          }
      }
      f16x8 pa[2][2];
#pragma unroll
      for (int qt = 0; qt < 2; ++qt)
#pragma unroll
        for (int kb = 0; kb < 2; ++kb)
          pa[qt][kb] = *(const f16x8*)(Pw + (qt * 16 + c) * 64 +
                                       (((kb * 4 + g) ^ sw) << 3));
      // O += P @ V from swizzled LDS (V^T rows)
      __builtin_amdgcn_s_setprio(1);
#pragma unroll
      for (int dt = 0; dt < 4; ++dt) {
        const _Float16* vr = Vb + (dt * 16 + c) * 64;
        f16x8 vf0 = *(const f16x8*)(vr + ((g ^ sw) << 3));
        f16x8 vf1 = *(const f16x8*)(vr + (((g ^ 4) ^ sw) << 3));
        acc[0][dt] = MFMA(pa[0][0], vf0, acc[0][dt]);
        acc[0][dt] = MFMA(pa[0][1], vf1, acc[0][dt]);
        acc[1][dt] = MFMA(pa[1][0], vf0, acc[1][dt]);
        acc[1][dt] = MFMA(pa[1][1], vf1, acc[1][dt]);
      }
      __builtin_amdgcn_s_setprio(0);
    }
  }
  // normalize + write O as [n, l, h*64+d] f16
#pragma unroll
  for (int qt = 0; qt < 2; ++qt) {
    float inv[4];
#pragma unroll
    for (int r = 0; r < 4; ++r) inv[r] = 1.f / ls[qt][r];
#pragma unroll
    for (int dt = 0; dt < 4; ++dt)
#pragma unroll
      for (int r = 0; r < 4; ++r) {
        const long rowq = qlo + qt * 16 + g * 4 + r;
        Ob[(n * 2048 + rowq) * 1024 + h * 64 + dt * 16 + c] =
            (_Float16)(acc[qt][dt][r] * inv[r]);
      }
  }
#undef STAGE
}

// ---------------------------------------------------------------------------
extern "C" void kernel_launch(void* const* d_in, const int* in_sizes, int n_in,
                              void* d_out, int out_size, void* d_ws, size_t ws_size,
                              hipStream_t stream) {
  const float* x = (const float*)d_in[0];
  // d_in[1] = attn_mask: fixed causal triu(k=1); handled analytically.
  const float* w_qkv = (const float*)d_in[2];
  const float* w_proj = (const float*)d_in[3];
  const float* b_proj = (const float*)d_in[4];
  const float* qg = (const float*)d_in[5];
  const float* qb = (const float*)d_in[6];
  const float* kg = (const float*)d_in[7];
  const float* kb = (const float*)d_in[8];

  char* ws = (char*)d_ws;
  _Float16* xb     = (_Float16*)(ws + 0);         // 16 MiB; reused as Ob later
  _Float16* wqkvb  = (_Float16*)(ws + 16777216);  // 6 MiB
  _Float16* wprojb = (_Float16*)(ws + 23068672);  // 2 MiB
  _Float16* qkvh   = (_Float16*)(ws + 25165824);  // 48 MiB [8192][3072]
  _Float16* Vt     = (_Float16*)(ws + 75497472);  // 16 MiB [64][64][2048]
  _Float16* Ob     = xb;                          // alias: xb dead after QKV GEMM

  f32_to_f16_kernel<<<4096, 256, 0, stream>>>(x, xb, 8388608);
  f32_to_f16_kernel<<<1536, 256, 0, stream>>>(w_qkv, wqkvb, 3145728);
  f32_to_f16_kernel<<<512, 256, 0, stream>>>(w_proj, wprojb, 1048576);

  gemm_bt<true><<<dim3(64, 24), 256, 0, stream>>>(xb, wqkvb, qkvh, nullptr,
                                                  8192, 3072, 1024);
  ln_pack_kernel<<<8192, 256, 0, stream>>>(qkvh, qg, qb, kg, kb);
  transpose_v_kernel<<<dim3(32, 64), 256, 0, stream>>>(qkvh, Vt);
  attn_kernel<<<dim3(64, 16), 256, 0, stream>>>(qkvh, Vt, Ob);
  gemm_bt<false><<<dim3(64, 8), 256, 0, stream>>>(Ob, wprojb, d_out, b_proj,
                                                  8192, 1024, 1024);
}

// Round 3
// 266.698 us; speedup vs baseline: 1.8268x; 1.1031x over previous
//
#include <hip/hip_runtime.h>

// ---------------------------------------------------------------------------
// Generalized causal attention, MI355X (gfx950).
// Pipeline: f32->f16 convert -> QKV GEMM (MFMA, global_load_lds) ->
// in-place head-LN (q scaled by hd^-0.5*log2e) -> V transpose ->
// flash attention (LDS-staged KV, dbuf, swizzled, defer-max softmax) ->
// proj GEMM (+bias) f32 out.
// ---------------------------------------------------------------------------

using f16x8 = __attribute__((ext_vector_type(8))) _Float16;
using f32x4 = __attribute__((ext_vector_type(4))) float;

#define MFMA(a, b, c) __builtin_amdgcn_mfma_f32_16x16x32_f16(a, b, c, 0, 0, 0)

__device__ __forceinline__ void gload_lds16(const void* g, void* l) {
  // LDS dest = wave-uniform base + lane*16 (HW behavior); global src per-lane.
  __builtin_amdgcn_global_load_lds(
      (const __attribute__((address_space(1))) unsigned int*)g,
      (__attribute__((address_space(3))) unsigned int*)l, 16, 0, 0);
}

// ---------------------------------------------------------------------------
__global__ __launch_bounds__(256) void f32_to_f16_kernel(
    const float* __restrict__ in, _Float16* __restrict__ out, int n) {
  int i = (blockIdx.x * 256 + threadIdx.x) * 8;
  if (i >= n) return;
  float4 a = *(const float4*)(in + i);
  float4 b = *(const float4*)(in + i + 4);
  f16x8 o;
  o[0] = (_Float16)a.x; o[1] = (_Float16)a.y; o[2] = (_Float16)a.z; o[3] = (_Float16)a.w;
  o[4] = (_Float16)b.x; o[5] = (_Float16)b.y; o[6] = (_Float16)b.z; o[7] = (_Float16)b.w;
  *(f16x8*)(out + i) = o;
}

// ---------------------------------------------------------------------------
// C[M,N] = A[M,K] @ B[N,K]^T, 128x128 tile, BK=32, 4 waves (2x2), m97-style.
template <bool F16OUT>
__global__ __launch_bounds__(256) void gemm_bt(
    const _Float16* __restrict__ A, const _Float16* __restrict__ B,
    void* __restrict__ Cout, const float* __restrict__ bias,
    int M, int N, int K) {
  __shared__ __align__(16) _Float16 As[128 * 32];  // [128 rows][32 k]
  __shared__ __align__(16) _Float16 Bs[128 * 32];
  const int tid = threadIdx.x;
  const int w = tid >> 6, lane = tid & 63;
  const int c = lane & 15, g = lane >> 4;
  const long mbase = (long)blockIdx.x * 128;
  const long nbase = (long)blockIdx.y * 128;
  const int wm = (w >> 1) * 64, wn = (w & 1) * 64;
  const int srow = w * 32 + (lane >> 2);
  const int scol = (lane & 3) * 8;

  f32x4 acc[4][4];
#pragma unroll
  for (int i = 0; i < 4; ++i)
#pragma unroll
    for (int j = 0; j < 4; ++j) acc[i][j] = f32x4{0.f, 0.f, 0.f, 0.f};

  for (int kt = 0; kt < K; kt += 32) {
    __syncthreads();  // previous tile consumed
    gload_lds16(A + (mbase + srow) * K + kt + scol, As + w * 1024);
    gload_lds16(A + (mbase + srow + 16) * K + kt + scol, As + w * 1024 + 512);
    gload_lds16(B + (nbase + srow) * K + kt + scol, Bs + w * 1024);
    gload_lds16(B + (nbase + srow + 16) * K + kt + scol, Bs + w * 1024 + 512);
    __syncthreads();  // drains vmcnt(0), staging visible
    f16x8 af[4], bfr[4];
#pragma unroll
    for (int mt = 0; mt < 4; ++mt)
      af[mt] = *(const f16x8*)(As + (wm + mt * 16 + c) * 32 + g * 8);
#pragma unroll
    for (int nt = 0; nt < 4; ++nt)
      bfr[nt] = *(const f16x8*)(Bs + (wn + nt * 16 + c) * 32 + g * 8);
#pragma unroll
    for (int mt = 0; mt < 4; ++mt)
#pragma unroll
      for (int nt = 0; nt < 4; ++nt)
        acc[mt][nt] = MFMA(af[mt], bfr[nt], acc[mt][nt]);
  }
#pragma unroll
  for (int nt = 0; nt < 4; ++nt) {
    const long col = nbase + wn + nt * 16 + c;
    const float bv = bias ? bias[col] : 0.f;
#pragma unroll
    for (int mt = 0; mt < 4; ++mt)
#pragma unroll
      for (int r = 0; r < 4; ++r) {
        const long row = mbase + wm + mt * 16 + g * 4 + r;
        const float v = acc[mt][nt][r] + bv;
        if constexpr (F16OUT)
          ((_Float16*)Cout)[row * N + col] = (_Float16)v;
        else
          ((float*)Cout)[row * N + col] = v;
      }
  }
}

// ---------------------------------------------------------------------------
// In-place LN over hd=64 for q (scaled by hd^-0.5*log2e) and k.
__global__ __launch_bounds__(256) void ln_pack_kernel(
    _Float16* __restrict__ qkv, const float* __restrict__ qg,
    const float* __restrict__ qb, const float* __restrict__ kg,
    const float* __restrict__ kb) {
  const int W = blockIdx.x * 4 + (threadIdx.x >> 6);
  const int lane = threadIdx.x & 63;
  const long row = W >> 2;
  const int e = (W & 3) * 512 + (lane >> 3) * 64 + (lane & 7) * 8;
  const int t = e >> 10;  // 0=q, 1=k (wave-uniform)
  const int d0 = (lane & 7) * 8;
  _Float16* p = qkv + row * 3072 + e;
  f16x8 v = *(const f16x8*)p;
  float f[8], sum = 0.f, sq = 0.f;
#pragma unroll
  for (int j = 0; j < 8; ++j) { f[j] = (float)v[j]; sum += f[j]; sq += f[j] * f[j]; }
#pragma unroll
  for (int msk = 1; msk < 8; msk <<= 1) {
    sum += __shfl_xor(sum, msk);
    sq += __shfl_xor(sq, msk);
  }
  const float mu = sum * 0.015625f;
  const float var = sq * 0.015625f - mu * mu;
  const float rstd = rsqrtf(var + 1e-5f);
  const float* gamma = t ? kg : qg;
  const float* beta = t ? kb : qb;
  const float sc = t ? 1.f : 0.1803368801111204f;  // hd^-0.5 * log2(e)
  f16x8 o;
#pragma unroll
  for (int j = 0; j < 8; ++j)
    o[j] = (_Float16)(((f[j] - mu) * rstd * gamma[d0 + j] + beta[d0 + j]) * sc);
  *(f16x8*)p = o;
}

// ---------------------------------------------------------------------------
// V transpose: qkv v-part [l][d] -> Vt[nh][d][l] (rows contiguous in l).
__global__ __launch_bounds__(256) void transpose_v_kernel(
    const _Float16* __restrict__ qkv, _Float16* __restrict__ Vt) {
  __shared__ __align__(16) _Float16 tile[64][80];
  const int nh = blockIdx.y;
  const long n = nh >> 4;
  const int h = nh & 15;
  const long lbase = (long)blockIdx.x * 64;
  const int t = threadIdx.x;
#pragma unroll
  for (int r = 0; r < 2; ++r) {
    const int l = (t + r * 256) >> 3;
    const int cc = (t & 7) * 8;
    f16x8 v = *(const f16x8*)(qkv + (n * 2048 + lbase + l) * 3072 + 2048 + h * 64 + cc);
    *(f16x8*)&tile[l][cc] = v;
  }
  __syncthreads();
  const int d = t >> 2, q = t & 3;
  f16x8 o0, o1;
#pragma unroll
  for (int i = 0; i < 8; ++i) {
    o0[i] = tile[q * 16 + i][d];
    o1[i] = tile[q * 16 + 8 + i][d];
  }
  _Float16* dst = Vt + ((long)nh * 64 + d) * 2048 + lbase + q * 16;
  *(f16x8*)dst = o0;
  *(f16x8*)(dst + 8) = o1;
}

// ---------------------------------------------------------------------------
// Flash attention, causal. Block = 4 waves; wave owns 32 q-rows; KV tiles of
// 64 rows staged cooperatively into LDS (double-buffered, XOR-swizzled via
// pre-swizzled global source — rule 21). exp2-domain online softmax with
// defer-max (T13) and end-of-loop denominator reduction.
__global__ __launch_bounds__(256) void attn_kernel(
    const _Float16* __restrict__ qkv, const _Float16* __restrict__ Vt,
    _Float16* __restrict__ Ob) {
  __shared__ __align__(16) _Float16 Ks[2][64 * 64];  // 8KB x2, rows=128B, swz
  __shared__ __align__(16) _Float16 Vs[2][64 * 64];  // V^T tiles, same layout
  __shared__ __align__(16) _Float16 Pl[4][32 * 64];  // per-wave P, swizzled
  const int w = threadIdx.x >> 6;
  const int lane = threadIdx.x & 63;
  const int c = lane & 15, g = lane >> 4;
  const int nh = blockIdx.x;
  const long n = nh >> 4;
  const int h = nh & 15;
  const int qtile = 15 - blockIdx.y;  // longest-first
  const int qlo_blk = qtile * 128;
  const int qlo = qlo_blk + w * 32;

  const _Float16* Qp = qkv + n * 2048 * 3072 + h * 64;
  const _Float16* Kq = Qp + 1024;                 // K base (row stride 3072)
  const _Float16* Vp = Vt + (long)nh * 64 * 2048; // V^T base (row stride 2048)

  const int sr8 = lane >> 3;
  const int scol = ((lane & 7) ^ sr8) * 8;

  const int nkv_blk = (qlo_blk + 191) >> 6;  // tiles needed by wave 3
  const int nkv_w = (qlo + 95) >> 6;         // tiles this wave computes

#define STAGE(buf, kv)                                                        \
  {                                                                           \
    const int kb_ = (kv) * 64;                                                \
    _Pragma("unroll") for (int i = 0; i < 2; ++i) {                           \
      const int idx = w * 2 + i;                                              \
      const int row = idx * 8 + sr8;                                          \
      gload_lds16(Kq + (long)(kb_ + row) * 3072 + scol, &Ks[buf][idx * 512]); \
      gload_lds16(Vp + (long)row * 2048 + kb_ + scol, &Vs[buf][idx * 512]);   \
    }                                                                         \
  }

  f16x8 qf[2][2];
#pragma unroll
  for (int qt = 0; qt < 2; ++qt)
#pragma unroll
    for (int db = 0; db < 2; ++db)
      qf[qt][db] = *(const f16x8*)(Qp + (long)(qlo + qt * 16 + c) * 3072 + db * 32 + g * 8);

  f32x4 acc[2][4];
  float m[2][4], ls[2][4];  // ls = per-lane PARTIAL denominator (reduced at end)
#pragma unroll
  for (int qt = 0; qt < 2; ++qt) {
#pragma unroll
    for (int dt = 0; dt < 4; ++dt) acc[qt][dt] = f32x4{0.f, 0.f, 0.f, 0.f};
#pragma unroll
    for (int r = 0; r < 4; ++r) { m[qt][r] = -1e30f; ls[qt][r] = 0.f; }
  }

  STAGE(0, 0);

  const int sw = c & 7;  // read-side XOR (row&7 == c&7 for all frag reads)
  _Float16* Pw = Pl[w];

  for (int kv = 0; kv < nkv_blk; ++kv) {
    const int cur = kv & 1;
    __syncthreads();  // staging(kv) drained (vmcnt0); buf[cur^1] free
    if (kv + 1 < nkv_blk) STAGE(cur ^ 1, kv + 1);

    if (kv < nkv_w) {
      const int kbase = kv * 64;
      const _Float16* Kb = Ks[cur];
      const _Float16* Vb = Vs[cur];
      f32x4 s[2][4];
#pragma unroll
      for (int qt = 0; qt < 2; ++qt)
#pragma unroll
        for (int kt = 0; kt < 4; ++kt) s[qt][kt] = f32x4{0.f, 0.f, 0.f, 0.f};
      // S = Q @ K^T from swizzled LDS
      __builtin_amdgcn_s_setprio(1);
#pragma unroll
      for (int kt = 0; kt < 4; ++kt) {
        const _Float16* kr = Kb + (kt * 16 + c) * 64;
        f16x8 kf0 = *(const f16x8*)(kr + ((g ^ sw) << 3));
        f16x8 kf1 = *(const f16x8*)(kr + (((g ^ 4) ^ sw) << 3));
        s[0][kt] = MFMA(qf[0][0], kf0, s[0][kt]);
        s[0][kt] = MFMA(qf[0][1], kf1, s[0][kt]);
        s[1][kt] = MFMA(qf[1][0], kf0, s[1][kt]);
        s[1][kt] = MFMA(qf[1][1], kf1, s[1][kt]);
      }
      __builtin_amdgcn_s_setprio(0);
      if (kbase + 63 > qlo) {  // causal mask on diagonal tiles
#pragma unroll
        for (int qt = 0; qt < 2; ++qt)
#pragma unroll
          for (int kt = 0; kt < 4; ++kt) {
            const int col = kbase + kt * 16 + c;
#pragma unroll
            for (int r = 0; r < 4; ++r)
              if (col > qlo + qt * 16 + g * 4 + r) s[qt][kt][r] = -1e30f;
          }
      }
      // online softmax (base 2), defer-max: skip rescale when max grows < 8
#pragma unroll
      for (int qt = 0; qt < 2; ++qt) {
        float mt[4];
#pragma unroll
        for (int r = 0; r < 4; ++r)
          mt[r] = fmaxf(fmaxf(fmaxf(s[qt][0][r], s[qt][1][r]), s[qt][2][r]),
                        s[qt][3][r]);  // v_max3 + v_max
#pragma unroll
        for (int r = 0; r < 4; ++r) {
          mt[r] = fmaxf(mt[r], __shfl_xor(mt[r], 1));
          mt[r] = fmaxf(mt[r], __shfl_xor(mt[r], 2));
          mt[r] = fmaxf(mt[r], __shfl_xor(mt[r], 4));
          mt[r] = fmaxf(mt[r], __shfl_xor(mt[r], 8));
        }
        bool need = false;
#pragma unroll
        for (int r = 0; r < 4; ++r) need |= (mt[r] > m[qt][r] + 8.f);
        if (__any(need)) {
#pragma unroll
          for (int r = 0; r < 4; ++r) {
            const float mn = fmaxf(m[qt][r], mt[r]);
            const float al = exp2f(m[qt][r] - mn);
            m[qt][r] = mn;
            ls[qt][r] *= al;
#pragma unroll
            for (int dt = 0; dt < 4; ++dt) acc[qt][dt][r] *= al;
          }
        }
        // P = exp2(s - m); per-lane partial denominator accumulation
#pragma unroll
        for (int r = 0; r < 4; ++r) {
          float rs = 0.f;
#pragma unroll
          for (int kt = 0; kt < 4; ++kt) {
            const float p = exp2f(s[qt][kt][r] - m[qt][r]);
            s[qt][kt][r] = p;
            rs += p;
          }
          ls[qt][r] += rs;
        }
        // P -> per-wave LDS, swizzled
#pragma unroll
        for (int kt = 0; kt < 4; ++kt)
#pragma unroll
          for (int r = 0; r < 4; ++r) {
            const int prow = qt * 16 + g * 4 + r;
            const int pblk = (kt * 2 + (c >> 3)) ^ (prow & 7);
            Pw[prow * 64 + pblk * 8 + (c & 7)] = (_Float16)s[qt][kt][r];
          }
      }
      f16x8 pa[2][2];
#pragma unroll
      for (int qt = 0; qt < 2; ++qt)
#pragma unroll
        for (int kb = 0; kb < 2; ++kb)
          pa[qt][kb] = *(const f16x8*)(Pw + (qt * 16 + c) * 64 +
                                       (((kb * 4 + g) ^ sw) << 3));
      // O += P @ V from swizzled LDS (V^T rows)
      __builtin_amdgcn_s_setprio(1);
#pragma unroll
      for (int dt = 0; dt < 4; ++dt) {
        const _Float16* vr = Vb + (dt * 16 + c) * 64;
        f16x8 vf0 = *(const f16x8*)(vr + ((g ^ sw) << 3));
        f16x8 vf1 = *(const f16x8*)(vr + (((g ^ 4) ^ sw) << 3));
        acc[0][dt] = MFMA(pa[0][0], vf0, acc[0][dt]);
        acc[0][dt] = MFMA(pa[0][1], vf1, acc[0][dt]);
        acc[1][dt] = MFMA(pa[1][0], vf0, acc[1][dt]);
        acc[1][dt] = MFMA(pa[1][1], vf1, acc[1][dt]);
      }
      __builtin_amdgcn_s_setprio(0);
    }
  }
  // reduce denominator across the 16-lane row group (once), normalize, write
#pragma unroll
  for (int qt = 0; qt < 2; ++qt) {
    float inv[4];
#pragma unroll
    for (int r = 0; r < 4; ++r) {
      float t = ls[qt][r];
      t += __shfl_xor(t, 1);
      t += __shfl_xor(t, 2);
      t += __shfl_xor(t, 4);
      t += __shfl_xor(t, 8);
      inv[r] = 1.f / t;
    }
#pragma unroll
    for (int dt = 0; dt < 4; ++dt)
#pragma unroll
      for (int r = 0; r < 4; ++r) {
        const long rowq = qlo + qt * 16 + g * 4 + r;
        Ob[(n * 2048 + rowq) * 1024 + h * 64 + dt * 16 + c] =
            (_Float16)(acc[qt][dt][r] * inv[r]);
      }
  }
#undef STAGE
}

// ---------------------------------------------------------------------------
extern "C" void kernel_launch(void* const* d_in, const int* in_sizes, int n_in,
                              void* d_out, int out_size, void* d_ws, size_t ws_size,
                              hipStream_t stream) {
  const float* x = (const float*)d_in[0];
  // d_in[1] = attn_mask: fixed causal triu(k=1); handled analytically.
  const float* w_qkv = (const float*)d_in[2];
  const float* w_proj = (const float*)d_in[3];
  const float* b_proj = (const float*)d_in[4];
  const float* qg = (const float*)d_in[5];
  const float* qb = (const float*)d_in[6];
  const float* kg = (const float*)d_in[7];
  const float* kb = (const float*)d_in[8];

  char* ws = (char*)d_ws;
  _Float16* xb     = (_Float16*)(ws + 0);         // 16 MiB; reused as Ob later
  _Float16* wqkvb  = (_Float16*)(ws + 16777216);  // 6 MiB
  _Float16* wprojb = (_Float16*)(ws + 23068672);  // 2 MiB
  _Float16* qkvh   = (_Float16*)(ws + 25165824);  // 48 MiB [8192][3072]
  _Float16* Vt     = (_Float16*)(ws + 75497472);  // 16 MiB [64][64][2048]
  _Float16* Ob     = xb;                          // alias: xb dead after QKV GEMM

  f32_to_f16_kernel<<<4096, 256, 0, stream>>>(x, xb, 8388608);
  f32_to_f16_kernel<<<1536, 256, 0, stream>>>(w_qkv, wqkvb, 3145728);
  f32_to_f16_kernel<<<512, 256, 0, stream>>>(w_proj, wprojb, 1048576);

  gemm_bt<true><<<dim3(64, 24), 256, 0, stream>>>(xb, wqkvb, qkvh, nullptr,
                                                  8192, 3072, 1024);
  ln_pack_kernel<<<8192, 256, 0, stream>>>(qkvh, qg, qb, kg, kb);
  transpose_v_kernel<<<dim3(32, 64), 256, 0, stream>>>(qkvh, Vt);
  attn_kernel<<<dim3(64, 16), 256, 0, stream>>>(qkvh, Vt, Ob);
  gemm_bt<false><<<dim3(64, 8), 256, 0, stream>>>(Ob, wprojb, d_out, b_proj,
                                                  8192, 1024, 1024);
}

// Round 4
// 219.771 us; speedup vs baseline: 2.2169x; 1.2135x over previous
//
#include <hip/hip_runtime.h>

// ---------------------------------------------------------------------------
// Generalized causal attention, MI355X (gfx950).
// Pipeline: f32->f16 convert -> QKV GEMM (MFMA, global_load_lds, fused
// head-LN epilogue, q pre-scaled by hd^-0.5*log2e) -> V transpose ->
// flash attention (32x32 swapped-QK^T, in-register softmax, cvt_pkrtz +
// permlane32_swap P redistribution, LDS-staged KV dbuf) -> proj GEMM f32 out.
// ---------------------------------------------------------------------------

using f16x8 = __attribute__((ext_vector_type(8))) _Float16;
using f16x4 = __attribute__((ext_vector_type(4))) _Float16;
using f16x2 = __attribute__((ext_vector_type(2))) _Float16;
using f32x4 = __attribute__((ext_vector_type(4))) float;
using f32x16 = __attribute__((ext_vector_type(16))) float;
using u32x4 = __attribute__((ext_vector_type(4))) unsigned int;

#define MFMA16(a, b, c) __builtin_amdgcn_mfma_f32_16x16x32_f16(a, b, c, 0, 0, 0)
#define MFMA32(a, b, c) __builtin_amdgcn_mfma_f32_32x32x16_f16(a, b, c, 0, 0, 0)

__device__ __forceinline__ void gload_lds16(const void* g, void* l) {
  // LDS dest = wave-uniform base + lane*16 (HW behavior); global src per-lane.
  __builtin_amdgcn_global_load_lds(
      (const __attribute__((address_space(1))) unsigned int*)g,
      (__attribute__((address_space(3))) unsigned int*)l, 16, 0, 0);
}

// ---------------------------------------------------------------------------
__global__ __launch_bounds__(256) void f32_to_f16_kernel(
    const float* __restrict__ in, _Float16* __restrict__ out, int n) {
  int i = (blockIdx.x * 256 + threadIdx.x) * 8;
  if (i >= n) return;
  float4 a = *(const float4*)(in + i);
  float4 b = *(const float4*)(in + i + 4);
  f16x8 o;
  o[0] = (_Float16)a.x; o[1] = (_Float16)a.y; o[2] = (_Float16)a.z; o[3] = (_Float16)a.w;
  o[4] = (_Float16)b.x; o[5] = (_Float16)b.y; o[6] = (_Float16)b.z; o[7] = (_Float16)b.w;
  *(f16x8*)(out + i) = o;
}

// ---------------------------------------------------------------------------
// C[M,N] = A[M,K] @ B[N,K]^T, 128x128 tile, BK=32, 4 waves (2x2), m97-style.
// MODE 0: f32 out + bias (proj). MODE 1: f16 out, fused per-head LN on the
// q/k column regions (cols<1024: q, LN+scale; 1024..2047: k, LN; else v).
template <int MODE>
__global__ __launch_bounds__(256) void gemm_bt(
    const _Float16* __restrict__ A, const _Float16* __restrict__ B,
    void* __restrict__ Cout, const float* __restrict__ bias,
    const float* __restrict__ qg, const float* __restrict__ qb,
    const float* __restrict__ kg, const float* __restrict__ kb,
    int M, int N, int K) {
  __shared__ __align__(16) _Float16 As[128 * 32];  // [128 rows][32 k]
  __shared__ __align__(16) _Float16 Bs[128 * 32];
  const int tid = threadIdx.x;
  const int w = tid >> 6, lane = tid & 63;
  const int c = lane & 15, g = lane >> 4;
  const long mbase = (long)blockIdx.x * 128;
  const long nbase = (long)blockIdx.y * 128;
  const int wm = (w >> 1) * 64, wn = (w & 1) * 64;
  const int srow = w * 32 + (lane >> 2);
  const int scol = (lane & 3) * 8;

  f32x4 acc[4][4];
#pragma unroll
  for (int i = 0; i < 4; ++i)
#pragma unroll
    for (int j = 0; j < 4; ++j) acc[i][j] = f32x4{0.f, 0.f, 0.f, 0.f};

  for (int kt = 0; kt < K; kt += 32) {
    __syncthreads();  // previous tile consumed
    gload_lds16(A + (mbase + srow) * K + kt + scol, As + w * 1024);
    gload_lds16(A + (mbase + srow + 16) * K + kt + scol, As + w * 1024 + 512);
    gload_lds16(B + (nbase + srow) * K + kt + scol, Bs + w * 1024);
    gload_lds16(B + (nbase + srow + 16) * K + kt + scol, Bs + w * 1024 + 512);
    __syncthreads();  // drains vmcnt(0), staging visible
    f16x8 af[4], bfr[4];
#pragma unroll
    for (int mt = 0; mt < 4; ++mt)
      af[mt] = *(const f16x8*)(As + (wm + mt * 16 + c) * 32 + g * 8);
#pragma unroll
    for (int nt = 0; nt < 4; ++nt)
      bfr[nt] = *(const f16x8*)(Bs + (wn + nt * 16 + c) * 32 + g * 8);
#pragma unroll
    for (int mt = 0; mt < 4; ++mt)
#pragma unroll
      for (int nt = 0; nt < 4; ++nt)
        acc[mt][nt] = MFMA16(af[mt], bfr[nt], acc[mt][nt]);
  }

  if constexpr (MODE == 1) {
    // Fused head-LN: each row's 64-wide head segment = acc[mt][0..3][r]
    // across the 16 c-lanes of this g-group.
    const int region = (int)(nbase >> 10);  // 0=q, 1=k, 2=v
    if (region < 2) {
      const float* gamma = region ? kg : qg;
      const float* beta = region ? kb : qb;
      float gam[4], bet[4];
#pragma unroll
      for (int nt = 0; nt < 4; ++nt) {
        gam[nt] = gamma[nt * 16 + c];
        bet[nt] = beta[nt * 16 + c];
      }
      const float sc = region ? 1.f : 0.1803368801111204f;  // hd^-0.5*log2(e)
#pragma unroll
      for (int mt = 0; mt < 4; ++mt)
#pragma unroll
        for (int r = 0; r < 4; ++r) {
          float s1 = 0.f, s2 = 0.f;
#pragma unroll
          for (int nt = 0; nt < 4; ++nt) {
            const float v = acc[mt][nt][r];
            s1 += v;
            s2 += v * v;
          }
#pragma unroll
          for (int msk = 1; msk < 16; msk <<= 1) {
            s1 += __shfl_xor(s1, msk);
            s2 += __shfl_xor(s2, msk);
          }
          const float mu = s1 * 0.015625f;
          const float rstd = rsqrtf(s2 * 0.015625f - mu * mu + 1e-5f);
#pragma unroll
          for (int nt = 0; nt < 4; ++nt)
            acc[mt][nt][r] =
                ((acc[mt][nt][r] - mu) * rstd * gam[nt] + bet[nt]) * sc;
        }
    }
  }

#pragma unroll
  for (int nt = 0; nt < 4; ++nt) {
    const long col = nbase + wn + nt * 16 + c;
    const float bv = (MODE == 0 && bias) ? bias[col] : 0.f;
#pragma unroll
    for (int mt = 0; mt < 4; ++mt)
#pragma unroll
      for (int r = 0; r < 4; ++r) {
        const long row = mbase + wm + mt * 16 + g * 4 + r;
        const float v = acc[mt][nt][r] + bv;
        if constexpr (MODE == 1)
          ((_Float16*)Cout)[row * N + col] = (_Float16)v;
        else
          ((float*)Cout)[row * N + col] = v;
      }
  }
}

// ---------------------------------------------------------------------------
// V transpose: qkv v-part [l][d] -> Vt[nh][d][l] (rows contiguous in l).
__global__ __launch_bounds__(256) void transpose_v_kernel(
    const _Float16* __restrict__ qkv, _Float16* __restrict__ Vt) {
  __shared__ __align__(16) _Float16 tile[64][80];
  const int nh = blockIdx.y;
  const long n = nh >> 4;
  const int h = nh & 15;
  const long lbase = (long)blockIdx.x * 64;
  const int t = threadIdx.x;
#pragma unroll
  for (int r = 0; r < 2; ++r) {
    const int l = (t + r * 256) >> 3;
    const int cc = (t & 7) * 8;
    f16x8 v = *(const f16x8*)(qkv + (n * 2048 + lbase + l) * 3072 + 2048 + h * 64 + cc);
    *(f16x8*)&tile[l][cc] = v;
  }
  __syncthreads();
  const int d = t >> 2, q = t & 3;
  f16x8 o0, o1;
#pragma unroll
  for (int i = 0; i < 8; ++i) {
    o0[i] = tile[q * 16 + i][d];
    o1[i] = tile[q * 16 + 8 + i][d];
  }
  _Float16* dst = Vt + ((long)nh * 64 + d) * 2048 + lbase + q * 16;
  *(f16x8*)dst = o0;
  *(f16x8*)(dst + 8) = o1;
}

// ---------------------------------------------------------------------------
// Flash attention, causal, 32x32x16 MFMA, swapped QK^T (S^T = K·Q^T) so each
// lane owns one q-row (col = lane&31). Softmax fully in-register; P routed
// to the PV B-fragment via cvt_pkrtz + v_permlane32_swap_b32 (no P LDS).
// KV tiles (64) staged into LDS, double-buffered, XOR-swizzled via
// pre-swizzled global source. exp2-domain, defer-max (T13).
__global__ __launch_bounds__(256) void attn_kernel(
    const _Float16* __restrict__ qkv, const _Float16* __restrict__ Vt,
    _Float16* __restrict__ Ob) {
  __shared__ __align__(16) _Float16 Ks[2][64 * 64];  // [kv][d], 16B-blk swz
  __shared__ __align__(16) _Float16 Vs[2][64 * 64];  // [d][kv], 16B-blk swz
  const int w = threadIdx.x >> 6;
  const int lane = threadIdx.x & 63;
  const int c5 = lane & 31;
  const int hi = lane >> 5;
  const int nh = blockIdx.x;
  const long n = nh >> 4;
  const int h = nh & 15;
  const int qtile = 15 - blockIdx.y;  // longest-first
  const int qlo_blk = qtile * 128;
  const int qlo = qlo_blk + w * 32;
  const int qrow = qlo + c5;  // this lane's q-row

  const _Float16* Qp = qkv + n * 2048 * 3072 + h * 64;
  const _Float16* Kq = Qp + 1024;                  // K base (row stride 3072)
  const _Float16* Vp = Vt + (long)nh * 64 * 2048;  // V^T base (row stride 2048)

  const int sr8 = lane >> 3;
  const int scol = ((lane & 7) ^ sr8) * 8;

  const int nkv_blk = (qlo_blk + 191) >> 6;  // tiles needed by wave 3
  const int nkv_w = (qlo + 95) >> 6;         // tiles this wave computes

#define STAGE(buf, kv)                                                        \
  {                                                                           \
    const int kb_ = (kv) * 64;                                                \
    _Pragma("unroll") for (int i = 0; i < 2; ++i) {                           \
      const int idx = w * 2 + i;                                              \
      const int row = idx * 8 + sr8;                                          \
      gload_lds16(Kq + (long)(kb_ + row) * 3072 + scol, &Ks[buf][idx * 512]); \
      gload_lds16(Vp + (long)row * 2048 + kb_ + scol, &Vs[buf][idx * 512]);   \
    }                                                                         \
  }

  // Q as B-fragment: lane needs Q[qrow][dc*16 + hi*8 .. +7], dc=0..3.
  f16x8 qf[4];
#pragma unroll
  for (int dc = 0; dc < 4; ++dc)
    qf[dc] = *(const f16x8*)(Qp + (long)qrow * 3072 + dc * 16 + hi * 8);

  f32x16 acc[2];
#pragma unroll
  for (int db = 0; db < 2; ++db)
#pragma unroll
    for (int r = 0; r < 16; ++r) acc[db][r] = 0.f;
  float m = -1e30f, ls = 0.f;  // per-lane (one q-row; partner lane shares m)

  STAGE(0, 0);

  const int swr = c5 & 7;  // row&7 for all fragment reads (rows = c5 mod 32)

  for (int kv = 0; kv < nkv_blk; ++kv) {
    const int cur = kv & 1;
    __syncthreads();  // staging(kv) drained (vmcnt0); buf[cur^1] free
    if (kv + 1 < nkv_blk) STAGE(cur ^ 1, kv + 1);

    if (kv < nkv_w) {
      const int kbase = kv * 64;
      const _Float16* Kb = Ks[cur];
      const _Float16* Vb = Vs[cur];
      // S^T[kv', q] for kv-chunks K=0 (rows c5), K=1 (rows 32+c5)
      f32x16 s0, s1;
#pragma unroll
      for (int r = 0; r < 16; ++r) { s0[r] = 0.f; s1[r] = 0.f; }
      __builtin_amdgcn_s_setprio(1);
#pragma unroll
      for (int dc = 0; dc < 4; ++dc) {
        const int b = (dc * 2 + hi) ^ swr;
        f16x8 kf0 = *(const f16x8*)(Kb + c5 * 64 + b * 8);
        f16x8 kf1 = *(const f16x8*)(Kb + (32 + c5) * 64 + b * 8);
        s0 = MFMA32(kf0, qf[dc], s0);
        s1 = MFMA32(kf1, qf[dc], s1);
      }
      __builtin_amdgcn_s_setprio(0);
      // causal mask: lane holds S[q=qrow][kv = kbase+32K+(r&3)+8(r>>2)+4hi]
      if (kbase + 63 > qlo) {
#pragma unroll
        for (int r = 0; r < 16; ++r) {
          const int mv = (r & 3) + 8 * (r >> 2) + 4 * hi;
          if (kbase + mv > qrow) s0[r] = -1e30f;
          if (kbase + 32 + mv > qrow) s1[r] = -1e30f;
        }
      }
      // in-register row max (row spread over the hi-pair only)
      float mm = s0[0];
#pragma unroll
      for (int r = 1; r < 16; ++r) mm = fmaxf(mm, s0[r]);
#pragma unroll
      for (int r = 0; r < 16; ++r) mm = fmaxf(mm, s1[r]);
      mm = fmaxf(mm, __shfl_xor(mm, 32));
      if (__any(mm > m + 8.f)) {  // defer-max
        const float mn = fmaxf(m, mm);
        const float al = exp2f(m - mn);
        m = mn;
        ls *= al;
#pragma unroll
        for (int db = 0; db < 2; ++db)
#pragma unroll
          for (int r = 0; r < 16; ++r) acc[db][r] *= al;
      }
      float ps = 0.f;
#pragma unroll
      for (int r = 0; r < 16; ++r) {
        const float p0 = exp2f(s0[r] - m);
        const float p1 = exp2f(s1[r] - m);
        s0[r] = p0; s1[r] = p1;
        ps += p0 + p1;
      }
      ls += ps;
      // pack P pairs: pk[K][r2][p] = f16x2(s[4r2+2p], s[4r2+2p+1])
      unsigned int pk0[4][2], pk1[4][2];
#pragma unroll
      for (int r2 = 0; r2 < 4; ++r2)
#pragma unroll
        for (int p = 0; p < 2; ++p) {
          pk0[r2][p] = __builtin_bit_cast(
              unsigned int,
              __builtin_amdgcn_cvt_pkrtz(s0[4 * r2 + 2 * p], s0[4 * r2 + 2 * p + 1]));
          pk1[r2][p] = __builtin_bit_cast(
              unsigned int,
              __builtin_amdgcn_cvt_pkrtz(s1[4 * r2 + 2 * p], s1[4 * r2 + 2 * p + 1]));
        }
      // redistribute to PV B-fragments: for kk-th 16-kv chunk, lane needs
      // k-slots 8hi+j -> own 4 + partner 4 of register pair (rx, ry=rx+1).
      // v_permlane32_swap_b32 X,Y: X'={X_lo,Y_lo}, Y'={X_hi,Y_hi}.
      f16x8 pB[4];
#pragma unroll
      for (int kk = 0; kk < 4; ++kk) {
        const int rx = (kk & 1) * 2;
        unsigned int x0 = (kk < 2) ? pk0[rx][0] : pk1[rx][0];
        unsigned int y0 = (kk < 2) ? pk0[rx + 1][0] : pk1[rx + 1][0];
        unsigned int x1 = (kk < 2) ? pk0[rx][1] : pk1[rx][1];
        unsigned int y1 = (kk < 2) ? pk0[rx + 1][1] : pk1[rx + 1][1];
        asm("v_permlane32_swap_b32 %0, %1" : "+v"(x0), "+v"(y0));
        asm("v_permlane32_swap_b32 %0, %1" : "+v"(x1), "+v"(y1));
        pB[kk] = __builtin_bit_cast(f16x8, u32x4{x0, x1, y0, y1});
      }
      // O^T += V^T · P : A = V^T rows d, B = P cols q
      __builtin_amdgcn_s_setprio(1);
#pragma unroll
      for (int db = 0; db < 2; ++db)
#pragma unroll
        for (int kk = 0; kk < 4; ++kk) {
          const int rowd = db * 32 + c5;
          const int bb = (kk * 2 + hi) ^ swr;
          f16x8 vf = *(const f16x8*)(Vb + rowd * 64 + bb * 8);
          acc[db] = MFMA32(vf, pB[kk], acc[db]);
        }
      __builtin_amdgcn_s_setprio(0);
    }
  }
  // finalize: denominator = own + partner partials; write O[q][d] (8B stores)
  const float lsr = ls + __shfl_xor(ls, 32);
  const float inv = 1.f / lsr;
  _Float16* ob = Ob + ((long)(n * 2048) + qrow) * 1024 + h * 64 + 4 * hi;
#pragma unroll
  for (int db = 0; db < 2; ++db)
#pragma unroll
    for (int r2 = 0; r2 < 4; ++r2) {
      f16x4 o;
#pragma unroll
      for (int j = 0; j < 4; ++j)
        o[j] = (_Float16)(acc[db][4 * r2 + j] * inv);
      *(f16x4*)(ob + db * 32 + 8 * r2) = o;
    }
#undef STAGE
}

// ---------------------------------------------------------------------------
extern "C" void kernel_launch(void* const* d_in, const int* in_sizes, int n_in,
                              void* d_out, int out_size, void* d_ws, size_t ws_size,
                              hipStream_t stream) {
  const float* x = (const float*)d_in[0];
  // d_in[1] = attn_mask: fixed causal triu(k=1); handled analytically.
  const float* w_qkv = (const float*)d_in[2];
  const float* w_proj = (const float*)d_in[3];
  const float* b_proj = (const float*)d_in[4];
  const float* qg = (const float*)d_in[5];
  const float* qb = (const float*)d_in[6];
  const float* kg = (const float*)d_in[7];
  const float* kb = (const float*)d_in[8];

  char* ws = (char*)d_ws;
  _Float16* xb     = (_Float16*)(ws + 0);         // 16 MiB; reused as Ob later
  _Float16* wqkvb  = (_Float16*)(ws + 16777216);  // 6 MiB
  _Float16* wprojb = (_Float16*)(ws + 23068672);  // 2 MiB
  _Float16* qkvh   = (_Float16*)(ws + 25165824);  // 48 MiB [8192][3072]
  _Float16* Vt     = (_Float16*)(ws + 75497472);  // 16 MiB [64][64][2048]
  _Float16* Ob     = xb;                          // alias: xb dead after QKV GEMM

  f32_to_f16_kernel<<<4096, 256, 0, stream>>>(x, xb, 8388608);
  f32_to_f16_kernel<<<1536, 256, 0, stream>>>(w_qkv, wqkvb, 3145728);
  f32_to_f16_kernel<<<512, 256, 0, stream>>>(w_proj, wprojb, 1048576);

  gemm_bt<1><<<dim3(64, 24), 256, 0, stream>>>(xb, wqkvb, qkvh, nullptr,
                                               qg, qb, kg, kb, 8192, 3072, 1024);
  transpose_v_kernel<<<dim3(32, 64), 256, 0, stream>>>(qkvh, Vt);
  attn_kernel<<<dim3(64, 16), 256, 0, stream>>>(qkvh, Vt, Ob);
  gemm_bt<0><<<dim3(64, 8), 256, 0, stream>>>(Ob, wprojb, d_out, b_proj,
                                              nullptr, nullptr, nullptr, nullptr,
                                              8192, 1024, 1024);
}